// Round 1
// baseline (601.959 us; speedup 1.0000x reference)
//
#include <hip/hip_runtime.h>
#include <math.h>

#define N     128
#define F_INN 128
#define HD    64
#define NC    40
#define BB    4096

#define CHUNK     16
#define XS_STRIDE 17   // CHUNK+1 -> conflict-free for row stride reads
#define YS_STRIDE 68   // HD+4    -> float4-aligned, <=4-way on writes

// ---------------------------------------------------------------------------
// prep1: build A_norm = D^-1/2 (A + I) D^-1/2 from tril edge weights.
// One block, 256 threads.
// ---------------------------------------------------------------------------
__global__ void prep_anorm(const float* __restrict__ edge_w,
                           float* __restrict__ An_out) {
    __shared__ float Ah[N][N + 1];
    __shared__ float dinv[N];
    const int t  = threadIdx.x;
    const int i  = t >> 1;            // row 0..127
    const int jh = (t & 1) * 64;      // column half
    for (int jj = 0; jj < 64; ++jj) {
        int j  = jh + jj;
        int hi = i >= j ? i : j;
        int lo = i >= j ? j : i;
        float a = edge_w[hi * (hi + 1) / 2 + lo];
        if (i == j) a += 1.0f;        // add_self_loops(fill=1)
        Ah[i][j] = a;
    }
    __syncthreads();
    if (t < N) {
        float s = 0.0f;
        for (int j = 0; j < N; ++j) s += Ah[t][j];
        dinv[t] = s > 0.0f ? 1.0f / sqrtf(s) : 0.0f;
    }
    __syncthreads();
    for (int jj = 0; jj < 64; ++jj) {
        int j = jh + jj;
        An_out[i * N + j] = dinv[i] * Ah[i][j] * dinv[j];
    }
}

// ---------------------------------------------------------------------------
// prep2: A2 = A_norm @ A_norm. Grid = N blocks (one row each), N threads.
// ---------------------------------------------------------------------------
__global__ void prep_a2(const float* __restrict__ An, float* __restrict__ A2) {
    const int i = blockIdx.x;
    const int j = threadIdx.x;
    float acc = 0.0f;
    for (int k = 0; k < N; ++k)
        acc += An[i * N + k] * An[k * N + j];  // An[i*N+k] is block-uniform (s_load)
    A2[i * N + j] = acc;
}

// ---------------------------------------------------------------------------
// main fused kernel: per batch element b
//   y = x[b] @ lin_w              (128x128 @ 128x64)
//   h = relu(A2 @ y + lin_b)      (128x128 @ 128x64)
//   pooled = relu(conv_w^T h + conv_b)      (64)
//   out[b] = pooled @ fc_w + fc_b           (40)
// 256 threads: thread (tm = t&31, hg = t>>5) owns rows {tm+32r} x cols
// {hg*8..hg*8+7}  -> acc[4][8] register tile.
// ---------------------------------------------------------------------------
__global__ __launch_bounds__(256, 2) void dgcnn_main(
    const float* __restrict__ x, const float* __restrict__ A2,
    const float* __restrict__ lin_w, const float* __restrict__ lin_b,
    const float* __restrict__ conv_w, const float* __restrict__ conv_b,
    const float* __restrict__ fc_w, const float* __restrict__ fc_b,
    float* __restrict__ out) {
    __shared__ float lw[F_INN * HD];      // 32768 B
    __shared__ float ys[N * YS_STRIDE];   // 34816 B
    __shared__ float xs[N * XS_STRIDE];   //  8704 B
    __shared__ float pooled[HD];

    const int t  = threadIdx.x;
    const int b  = blockIdx.x;
    const int tm = t & 31;
    const int hg = t >> 5;     // 0..7
    const int h0 = hg * 8;

    // stage lin_w (8192 floats) into LDS, coalesced float4
    {
        const float4* g = (const float4*)lin_w;
        float4* s = (float4*)lw;
#pragma unroll
        for (int r = 0; r < 8; ++r) s[t + 256 * r] = g[t + 256 * r];
    }

    float acc[4][8];
#pragma unroll
    for (int r = 0; r < 4; ++r)
#pragma unroll
        for (int q = 0; q < 8; ++q) acc[r][q] = 0.0f;

    const float* xb = x + (size_t)b * (N * F_INN);

    // ---------------- Phase 1: y = x @ lin_w ----------------
    for (int f0 = 0; f0 < F_INN; f0 += CHUNK) {
        __syncthreads();
        {
            const float4* g = (const float4*)xb;  // row = 32 float4
#pragma unroll
            for (int r = 0; r < 2; ++r) {
                int l4 = t + 256 * r;   // 0..511
                int n  = l4 >> 2;       // 0..127
                int fq = l4 & 3;        // 0..3
                float4 v = g[n * 32 + (f0 >> 2) + fq];
                float* d = &xs[n * XS_STRIDE + fq * 4];
                d[0] = v.x; d[1] = v.y; d[2] = v.z; d[3] = v.w;
            }
        }
        __syncthreads();
#pragma unroll
        for (int f = 0; f < CHUNK; ++f) {
            float av[4];
#pragma unroll
            for (int r = 0; r < 4; ++r) av[r] = xs[(tm + 32 * r) * XS_STRIDE + f];
            const float4* lr = (const float4*)&lw[(f0 + f) * HD];
            float4 w0 = lr[hg * 2];
            float4 w1 = lr[hg * 2 + 1];
            float wv[8] = {w0.x, w0.y, w0.z, w0.w, w1.x, w1.y, w1.z, w1.w};
#pragma unroll
            for (int r = 0; r < 4; ++r)
#pragma unroll
                for (int q = 0; q < 8; ++q)
                    acc[r][q] = fmaf(av[r], wv[q], acc[r][q]);
        }
    }

    // write y to LDS, reset accumulators
#pragma unroll
    for (int r = 0; r < 4; ++r) {
        int n = tm + 32 * r;
#pragma unroll
        for (int q = 0; q < 8; ++q) {
            ys[n * YS_STRIDE + h0 + q] = acc[r][q];
            acc[r][q] = 0.0f;
        }
    }

    // ---------------- Phase 2: h = A2 @ y ----------------
    for (int j0 = 0; j0 < N; j0 += CHUNK) {
        __syncthreads();   // also guards ys writes above on first iter
        {
            const float4* g = (const float4*)A2;
#pragma unroll
            for (int r = 0; r < 2; ++r) {
                int l4 = t + 256 * r;
                int n  = l4 >> 2;
                int jq = l4 & 3;
                float4 v = g[n * 32 + (j0 >> 2) + jq];
                float* d = &xs[n * XS_STRIDE + jq * 4];
                d[0] = v.x; d[1] = v.y; d[2] = v.z; d[3] = v.w;
            }
        }
        __syncthreads();
#pragma unroll
        for (int j = 0; j < CHUNK; ++j) {
            float av[4];
#pragma unroll
            for (int r = 0; r < 4; ++r) av[r] = xs[(tm + 32 * r) * XS_STRIDE + j];
            const float4* yr = (const float4*)&ys[(j0 + j) * YS_STRIDE];
            float4 w0 = yr[hg * 2];
            float4 w1 = yr[hg * 2 + 1];
            float wv[8] = {w0.x, w0.y, w0.z, w0.w, w1.x, w1.y, w1.z, w1.w};
#pragma unroll
            for (int r = 0; r < 4; ++r)
#pragma unroll
                for (int q = 0; q < 8; ++q)
                    acc[r][q] = fmaf(av[r], wv[q], acc[r][q]);
        }
    }

    __syncthreads();  // everyone done reading ys

    // epilogue: h = relu(acc + lin_b); store conv_w[n]*h for pooling
#pragma unroll
    for (int r = 0; r < 4; ++r) {
        int n = tm + 32 * r;
        float cw = conv_w[n];
#pragma unroll
        for (int q = 0; q < 8; ++q) {
            float v = acc[r][q] + lin_b[h0 + q];
            v = fmaxf(v, 0.0f);
            ys[n * YS_STRIDE + h0 + q] = v * cw;
        }
    }
    __syncthreads();

    // pooled[h] = relu(sum_n conv_w[n]*h[n,h] + conv_b)
    if (t < HD) {
        float s = 0.0f;
        for (int n = 0; n < N; ++n) s += ys[n * YS_STRIDE + t];
        pooled[t] = fmaxf(s + conv_b[0], 0.0f);
    }
    __syncthreads();

    // out[b] = pooled @ fc_w + fc_b
    if (t < NC) {
        float o = fc_b[t];
        for (int h = 0; h < HD; ++h) o += pooled[h] * fc_w[h * NC + t];
        out[(size_t)b * NC + t] = o;
    }
}

// ---------------------------------------------------------------------------
extern "C" void kernel_launch(void* const* d_in, const int* in_sizes, int n_in,
                              void* d_out, int out_size, void* d_ws, size_t ws_size,
                              hipStream_t stream) {
    const float* x      = (const float*)d_in[0];
    const float* edge_w = (const float*)d_in[1];
    const float* lin_w  = (const float*)d_in[2];
    const float* lin_b  = (const float*)d_in[3];
    const float* conv_w = (const float*)d_in[4];
    const float* conv_b = (const float*)d_in[5];
    const float* fc_w   = (const float*)d_in[6];
    const float* fc_b   = (const float*)d_in[7];
    float* out = (float*)d_out;

    float* A2 = (float*)d_ws;       // 16384 floats
    float* An = A2 + N * N;         // 16384 floats

    prep_anorm<<<1, 256, 0, stream>>>(edge_w, An);
    prep_a2<<<N, N, 0, stream>>>(An, A2);
    dgcnn_main<<<BB, 256, 0, stream>>>(x, A2, lin_w, lin_b, conv_w, conv_b,
                                       fc_w, fc_b, out);
}